// Round 6
// baseline (884.368 us; speedup 1.0000x reference)
//
#include <hip/hip_runtime.h>

// BetaBernoulliMixture, output [5, B, T] = {a1, b1, a2, b2, post_mixweight}
//
// Ledger (kernel-only = dur_us - ~430us harness fill; floor 805MB ~ 130us):
//   R3 block/row 256thr + NT .......... ~330us
//   R4 wave/row, 0 barriers ........... ~330us  (sync exonerated)
//   R5 1024thr, 16KB bursts ........... ~310us  (footprint/burst exonerated)
//   R6 plain cached stores ............ ~308us  (NT exonerated)
//   R7 plane-split .................... ~365us  (worse; streams/worker exonerated)
//   R8 phase-lagged stores ............ ~312us  (set/bank aliasing exonerated)
// Six nulls => choose next edit from DATA, not theory. We have never seen
// bbm's own PMCs (it is always < the 421-445us fills, so it never makes the
// top-5 counter table).
//
// R9 = MEASUREMENT ROUND: run the exact R6 kernel as ONE dispatch doing the
// work TWICE (grid = 2*B, row = blockIdx.x % Bn). Both halves write
// identical values to identical addresses (idempotent; racing stores of
// identical bytes are benign). The ~620us dispatch tops the counter table
// -> first-ever direct read of bbm's VALUBusy / Occupancy / FETCH_SIZE /
// WRITE_SIZE. Decides between: (a) residual 2x write amplification
// (WRITE ~ 2.6e6 KB), (b) memory-system stall (low VALUBusy, low BW),
// (c) VALU/latency bound (high VALUBusy). dur_us regresses ~+310us this
// round by design; best structure (R6) is unchanged underneath.

#define BLOCK 1024
#define VEC 4
#define NWAVES (BLOCK / 64)   // 16

typedef float v4f __attribute__((ext_vector_type(4)));

__global__ __launch_bounds__(BLOCK, 4) void bbm_kernel(
    const float* __restrict__ obs,
    const float* __restrict__ alpha1, const float* __restrict__ beta1,
    const float* __restrict__ alpha2, const float* __restrict__ beta2,
    const float* __restrict__ mixw,
    float* __restrict__ out,
    int T, size_t bt, int Bn)
{
    int row = blockIdx.x;
    if (row >= Bn) row -= Bn;          // second copy of the work: same rows
    const int tid  = threadIdx.x;
    const int lane = tid & 63;
    const int wid  = tid >> 6;

    __shared__ int   sPart[NWAVES];
    __shared__ float dPart[NWAVES];

    const float A1 = alpha1[row], B1 = beta1[row];
    const float A2 = alpha2[row], B2 = beta2[row];
    const float w  = mixw[0];
    const float AB1 = A1 + B1, AB2 = A2 + B2;
    const float w2 = 1.0f - w;

    const float* __restrict__ orow = obs + (size_t)row * T;
    float* __restrict__ obase = out + (size_t)row * T;

    const unsigned long long lt_mask = ((unsigned long long)1 << lane) - 1ull;

    int   carry_s = 0;
    float carry_d = 0.0f;

    const int EPB  = BLOCK * VEC;       // 4096 elements per block-segment
    const int segs = T / EPB;           // 2 for T=8192

    v4f cur = *(const v4f*)(orow + tid * VEC);

    for (int seg = 0; seg < segs; ++seg) {
        const int t0 = seg * EPB + tid * VEC;

        int bit[VEC], sloc[VEC];
        int ts = 0;
        #pragma unroll
        for (int j = 0; j < VEC; ++j) { bit[j] = cur[j] > 0.5f; sloc[j] = ts; ts += bit[j]; }

        unsigned long long m0 = __ballot(bit[0]);
        unsigned long long m1 = __ballot(bit[1]);
        unsigned long long m2 = __ballot(bit[2]);
        unsigned long long m3 = __ballot(bit[3]);
        const int wave_excl = __builtin_popcountll(m0 & lt_mask)
                            + __builtin_popcountll(m1 & lt_mask)
                            + __builtin_popcountll(m2 & lt_mask)
                            + __builtin_popcountll(m3 & lt_mask);
        const int wave_tot  = __builtin_popcountll(m0) + __builtin_popcountll(m1)
                            + __builtin_popcountll(m2) + __builtin_popcountll(m3);
        if (lane == 0) sPart[wid] = wave_tot;
        __syncthreads();
        int prior = 0, total = 0;
        #pragma unroll
        for (int wI = 0; wI < NWAVES; ++wI) {
            int p = sPart[wI];
            total += p;
            if (wI < wid) prior += p;
        }
        const int tbase_s = carry_s + prior + wave_excl;

        float dloc[VEC];
        float td = 0.0f;
        #pragma unroll
        for (int j = 0; j < VEC; ++j) {
            const float ft = (float)(t0 + j);
            const float fs = (float)(tbase_s + sloc[j]);
            const float fp = ft - fs;
            const float sel1 = bit[j] ? (A1 + fs) : (B1 + fp);
            const float sel2 = bit[j] ? (A2 + fs) : (B2 + fp);
            const float delta = __logf(sel2 * (AB1 + ft)) - __logf(sel1 * (AB2 + ft));
            dloc[j] = td;
            td += delta;
        }

        float incl_d = td;
        #pragma unroll
        for (int off = 1; off < 64; off <<= 1) {
            float n = __shfl_up(incl_d, off, 64);
            if (lane >= off) incl_d += n;
        }
        if (lane == 63) dPart[wid] = incl_d;
        __syncthreads();
        float priord = 0.0f, totald = 0.0f;
        #pragma unroll
        for (int wI = 0; wI < NWAVES; ++wI) {
            float p = dPart[wI];
            totald += p;
            if (wI < wid) priord += p;
        }
        const float tbase_d = carry_d + priord + (incl_d - td);

        v4f nxt;
        if (seg + 1 < segs) nxt = *(const v4f*)(orow + (seg + 1) * EPB + tid * VEC);

        v4f va1, vb1, va2, vb2, vpm;
        #pragma unroll
        for (int j = 0; j < VEC; ++j) {
            const float ft = (float)(t0 + j);
            const float fs = (float)(tbase_s + sloc[j]);
            const float fp = ft - fs;
            const float d  = tbase_d + dloc[j];
            va1[j] = A1 + fs;
            vb1[j] = B1 + fp;
            va2[j] = A2 + fs;
            vb2[j] = B2 + fp;
            vpm[j] = __fdividef(w, w + w2 * __expf(d));
        }
        float* p = obase + t0;
        *(v4f*)(p)          = va1;
        *(v4f*)(p + bt)     = vb1;
        *(v4f*)(p + 2 * bt) = va2;
        *(v4f*)(p + 3 * bt) = vb2;
        *(v4f*)(p + 4 * bt) = vpm;

        carry_s += total;
        carry_d += totald;
        cur = nxt;
    }
}

extern "C" void kernel_launch(void* const* d_in, const int* in_sizes, int n_in,
                              void* d_out, int out_size, void* d_ws, size_t ws_size,
                              hipStream_t stream) {
    const float* obs    = (const float*)d_in[0];
    const float* alpha1 = (const float*)d_in[1];
    const float* beta1  = (const float*)d_in[2];
    const float* alpha2 = (const float*)d_in[3];
    const float* beta2  = (const float*)d_in[4];
    const float* mixw   = (const float*)d_in[5];

    const int Bn = in_sizes[1];
    const int Tn = in_sizes[0] / Bn;
    const size_t bt = (size_t)Bn * (size_t)Tn;

    // MEASUREMENT: one dispatch, work done twice -> dispatch ~620us tops the
    // rocprof table and exposes bbm's own PMCs for the first time.
    bbm_kernel<<<Bn * 2, BLOCK, 0, stream>>>(obs, alpha1, beta1, alpha2, beta2,
                                             mixw, (float*)d_out, Tn, bt, Bn);
}

// Round 7
// 757.651 us; speedup vs baseline: 1.1672x; 1.1672x over previous
//
#include <hip/hip_runtime.h>

// BetaBernoulliMixture, output [5, B, T] = {a1, b1, a2, b2, post_mixweight}
//
// Ledger (kernel-only = dur_us - ~430us harness fill; floor 805MB ~130us):
//   R3..R8: six structural/pattern experiments all ~305-330us (sync,
//   footprint, burst, NT, stream-count, phase aliasing ALL exonerated).
//   R9 (work x2, cache-idempotent): dur +146us only => exec cost of the
//   whole workload with memory free is ~146us; kernel ~= exec(146) +
//   mem(160 @ ~5TB/s mixed, near ceiling) SERIALIZED.
//
// R10: shrink exec + overlap it with the store drain.
//  - one-shot: BLOCK=1024 x 8 elem/thread = T=8192. No loop, no carries.
//    Two lane-contiguous float4 halves (A: [0,4096), B: [4096,8192)) fused
//    into ONE ballot phase + ONE scan phase => 2 barriers per block total.
//  - all 10 stores issue at the very end, after the last barrier: no
//    __syncthreads ever vmcnt(0)-drains them; drain overlaps the next
//    block's startup on the same CU (block succession = pipeline).
//  - exec trims: mbcnt for ballot-exclusive counts, raw v_log/v_exp via
//    log2-domain d accumulation (no ln2 fixup muls), scalar popc for wave
//    totals, int2/float2-packed LDS partials.

#define BLOCK 1024
#define NW (BLOCK / 64)     // 16 waves

typedef float v4f __attribute__((ext_vector_type(4)));

__device__ __forceinline__ unsigned mbcnt_excl(unsigned long long m, unsigned base) {
    return __builtin_amdgcn_mbcnt_hi((unsigned)(m >> 32),
           __builtin_amdgcn_mbcnt_lo((unsigned)(m & 0xffffffffu), base));
}

__global__ __launch_bounds__(BLOCK, 4) void bbm_oneshot(
    const float* __restrict__ obs,
    const float* __restrict__ alpha1, const float* __restrict__ beta1,
    const float* __restrict__ alpha2, const float* __restrict__ beta2,
    const float* __restrict__ mixw,
    float* __restrict__ out,
    size_t bt)
{
    const int T    = 2 * BLOCK * 4;      // 8192 (specialized)
    const int HALF = BLOCK * 4;          // 4096
    const int row  = blockIdx.x;
    const int tid  = threadIdx.x;
    const int lane = tid & 63;
    const int wid  = tid >> 6;

    __shared__ int2   sP[NW];
    __shared__ float2 dP[NW];

    const float A1 = alpha1[row], B1 = beta1[row];
    const float A2 = alpha2[row], B2 = beta2[row];
    const float w  = mixw[0];
    const float AB1 = A1 + B1, AB2 = A2 + B2;
    const float w2 = 1.0f - w;

    const float* __restrict__ orow = obs + (size_t)row * T;
    float* __restrict__ obase = out + (size_t)row * T;

    const int t0A = tid * 4;
    const int t0B = HALF + tid * 4;

    // ---- load both halves (lane-contiguous float4) ----
    v4f curA = *(const v4f*)(orow + t0A);
    v4f curB = *(const v4f*)(orow + t0B);

    // ---- bits + thread-local exclusive prefixes ----
    int bitA[4], slA[4], bitB[4], slB[4];
    int tsA = 0, tsB = 0;
    #pragma unroll
    for (int j = 0; j < 4; ++j) { bitA[j] = curA[j] > 0.5f; slA[j] = tsA; tsA += bitA[j]; }
    #pragma unroll
    for (int j = 0; j < 4; ++j) { bitB[j] = curB[j] > 0.5f; slB[j] = tsB; tsB += bitB[j]; }

    // ---- ballots: 8 masks; exclusive counts via mbcnt; totals via scalar popc ----
    unsigned long long mA0 = __ballot(bitA[0]), mA1 = __ballot(bitA[1]);
    unsigned long long mA2 = __ballot(bitA[2]), mA3 = __ballot(bitA[3]);
    unsigned long long mB0 = __ballot(bitB[0]), mB1 = __ballot(bitB[1]);
    unsigned long long mB2 = __ballot(bitB[2]), mB3 = __ballot(bitB[3]);

    const unsigned exA = mbcnt_excl(mA3, mbcnt_excl(mA2, mbcnt_excl(mA1, mbcnt_excl(mA0, 0))));
    const unsigned exB = mbcnt_excl(mB3, mbcnt_excl(mB2, mbcnt_excl(mB1, mbcnt_excl(mB0, 0))));
    const int wtotA = __builtin_popcountll(mA0) + __builtin_popcountll(mA1)
                    + __builtin_popcountll(mA2) + __builtin_popcountll(mA3);
    const int wtotB = __builtin_popcountll(mB0) + __builtin_popcountll(mB1)
                    + __builtin_popcountll(mB2) + __builtin_popcountll(mB3);

    if (lane == 0) sP[wid] = make_int2(wtotA, wtotB);
    __syncthreads();                                  // barrier #1
    int priorA = 0, totalA = 0, priorB = 0;
    #pragma unroll
    for (int wI = 0; wI < NW; ++wI) {
        const int2 p = sP[wI];
        totalA += p.x;
        if (wI < wid) { priorA += p.x; priorB += p.y; }
    }
    const int baseAs = priorA + (int)exA;
    const int baseBs = totalA + priorB + (int)exB;

    // ---- deltas in log2 domain + thread-local prefixes ----
    float dlA[4], dlB[4];
    float tdA = 0.0f, tdB = 0.0f;
    #pragma unroll
    for (int j = 0; j < 4; ++j) {
        const float ft = (float)(t0A + j);
        const float fs = (float)(baseAs + slA[j]);
        const float fp = ft - fs;
        const float s1 = bitA[j] ? (A1 + fs) : (B1 + fp);
        const float s2 = bitA[j] ? (A2 + fs) : (B2 + fp);
        const float dl = __builtin_amdgcn_logf(s2 * (AB1 + ft))
                       - __builtin_amdgcn_logf(s1 * (AB2 + ft));   // log2 units
        dlA[j] = tdA; tdA += dl;
    }
    #pragma unroll
    for (int j = 0; j < 4; ++j) {
        const float ft = (float)(t0B + j);
        const float fs = (float)(baseBs + slB[j]);
        const float fp = ft - fs;
        const float s1 = bitB[j] ? (A1 + fs) : (B1 + fp);
        const float s2 = bitB[j] ? (A2 + fs) : (B2 + fp);
        const float dl = __builtin_amdgcn_logf(s2 * (AB1 + ft))
                       - __builtin_amdgcn_logf(s1 * (AB2 + ft));
        dlB[j] = tdB; tdB += dl;
    }

    // ---- wave shuffle-scan over per-thread totals (both halves per level) ----
    float inclA = tdA, inclB = tdB;
    #pragma unroll
    for (int off = 1; off < 64; off <<= 1) {
        const float nA = __shfl_up(inclA, off, 64);
        const float nB = __shfl_up(inclB, off, 64);
        if (lane >= off) { inclA += nA; inclB += nB; }
    }
    if (lane == 63) dP[wid] = make_float2(inclA, inclB);
    __syncthreads();                                  // barrier #2 (last)
    float priordA = 0.0f, totaldA = 0.0f, priordB = 0.0f;
    #pragma unroll
    for (int wI = 0; wI < NW; ++wI) {
        const float2 p = dP[wI];
        totaldA += p.x;
        if (wI < wid) { priordA += p.x; priordB += p.y; }
    }
    const float baseAd = priordA + (inclA - tdA);
    const float baseBd = totaldA + priordB + (inclB - tdB);

    // ---- outputs: compute both halves, then ALL stores at the tail ----
    v4f a1A, b1A, a2A, b2A, pmA, a1B, b1B, a2B, b2B, pmB;
    #pragma unroll
    for (int j = 0; j < 4; ++j) {
        const float ft = (float)(t0A + j);
        const float fs = (float)(baseAs + slA[j]);
        const float fp = ft - fs;
        const float d  = baseAd + dlA[j];
        a1A[j] = A1 + fs;
        b1A[j] = B1 + fp;
        a2A[j] = A2 + fs;
        b2A[j] = B2 + fp;
        pmA[j] = __fdividef(w, w + w2 * __builtin_amdgcn_exp2f(d));
    }
    #pragma unroll
    for (int j = 0; j < 4; ++j) {
        const float ft = (float)(t0B + j);
        const float fs = (float)(baseBs + slB[j]);
        const float fp = ft - fs;
        const float d  = baseBd + dlB[j];
        a1B[j] = A1 + fs;
        b1B[j] = B1 + fp;
        a2B[j] = A2 + fs;
        b2B[j] = B2 + fp;
        pmB[j] = __fdividef(w, w + w2 * __builtin_amdgcn_exp2f(d));
    }

    float* p = obase;
    *(v4f*)(p + t0A)          = a1A;  *(v4f*)(p + t0B)          = a1B;
    *(v4f*)(p + bt + t0A)     = b1A;  *(v4f*)(p + bt + t0B)     = b1B;
    *(v4f*)(p + 2 * bt + t0A) = a2A;  *(v4f*)(p + 2 * bt + t0B) = a2B;
    *(v4f*)(p + 3 * bt + t0A) = b2A;  *(v4f*)(p + 3 * bt + t0B) = b2B;
    *(v4f*)(p + 4 * bt + t0A) = pmA;  *(v4f*)(p + 4 * bt + t0B) = pmB;
}

// ---- generic fallback (R6 structure) for T != 8192 ----
#define GBLOCK 1024
#define GVEC 4
#define GNW (GBLOCK / 64)

__global__ __launch_bounds__(GBLOCK, 4) void bbm_generic(
    const float* __restrict__ obs,
    const float* __restrict__ alpha1, const float* __restrict__ beta1,
    const float* __restrict__ alpha2, const float* __restrict__ beta2,
    const float* __restrict__ mixw,
    float* __restrict__ out,
    int T, size_t bt)
{
    const int row  = blockIdx.x;
    const int tid  = threadIdx.x;
    const int lane = tid & 63;
    const int wid  = tid >> 6;

    __shared__ int   sPart[GNW];
    __shared__ float dPart[GNW];

    const float A1 = alpha1[row], B1 = beta1[row];
    const float A2 = alpha2[row], B2 = beta2[row];
    const float w  = mixw[0];
    const float AB1 = A1 + B1, AB2 = A2 + B2;
    const float w2 = 1.0f - w;

    const float* __restrict__ orow = obs + (size_t)row * T;
    float* __restrict__ obase = out + (size_t)row * T;

    const unsigned long long lt_mask = ((unsigned long long)1 << lane) - 1ull;

    int   carry_s = 0;
    float carry_d = 0.0f;

    const int EPB  = GBLOCK * GVEC;
    const int segs = T / EPB;

    v4f cur = *(const v4f*)(orow + tid * GVEC);

    for (int seg = 0; seg < segs; ++seg) {
        const int t0 = seg * EPB + tid * GVEC;

        int bit[GVEC], sloc[GVEC];
        int ts = 0;
        #pragma unroll
        for (int j = 0; j < GVEC; ++j) { bit[j] = cur[j] > 0.5f; sloc[j] = ts; ts += bit[j]; }

        unsigned long long m0 = __ballot(bit[0]);
        unsigned long long m1 = __ballot(bit[1]);
        unsigned long long m2 = __ballot(bit[2]);
        unsigned long long m3 = __ballot(bit[3]);
        const int wave_excl = __builtin_popcountll(m0 & lt_mask)
                            + __builtin_popcountll(m1 & lt_mask)
                            + __builtin_popcountll(m2 & lt_mask)
                            + __builtin_popcountll(m3 & lt_mask);
        const int wave_tot  = __builtin_popcountll(m0) + __builtin_popcountll(m1)
                            + __builtin_popcountll(m2) + __builtin_popcountll(m3);
        if (lane == 0) sPart[wid] = wave_tot;
        __syncthreads();
        int prior = 0, total = 0;
        #pragma unroll
        for (int wI = 0; wI < GNW; ++wI) {
            int p = sPart[wI];
            total += p;
            if (wI < wid) prior += p;
        }
        const int tbase_s = carry_s + prior + wave_excl;

        float dloc[GVEC];
        float td = 0.0f;
        #pragma unroll
        for (int j = 0; j < GVEC; ++j) {
            const float ft = (float)(t0 + j);
            const float fs = (float)(tbase_s + sloc[j]);
            const float fp = ft - fs;
            const float sel1 = bit[j] ? (A1 + fs) : (B1 + fp);
            const float sel2 = bit[j] ? (A2 + fs) : (B2 + fp);
            const float delta = __logf(sel2 * (AB1 + ft)) - __logf(sel1 * (AB2 + ft));
            dloc[j] = td;
            td += delta;
        }

        float incl_d = td;
        #pragma unroll
        for (int off = 1; off < 64; off <<= 1) {
            float n = __shfl_up(incl_d, off, 64);
            if (lane >= off) incl_d += n;
        }
        if (lane == 63) dPart[wid] = incl_d;
        __syncthreads();
        float priord = 0.0f, totald = 0.0f;
        #pragma unroll
        for (int wI = 0; wI < GNW; ++wI) {
            float p = dPart[wI];
            totald += p;
            if (wI < wid) priord += p;
        }
        const float tbase_d = carry_d + priord + (incl_d - td);

        v4f nxt;
        if (seg + 1 < segs) nxt = *(const v4f*)(orow + (seg + 1) * EPB + tid * GVEC);

        v4f va1, vb1, va2, vb2, vpm;
        #pragma unroll
        for (int j = 0; j < GVEC; ++j) {
            const float ft = (float)(t0 + j);
            const float fs = (float)(tbase_s + sloc[j]);
            const float fp = ft - fs;
            const float d  = tbase_d + dloc[j];
            va1[j] = A1 + fs;
            vb1[j] = B1 + fp;
            va2[j] = A2 + fs;
            vb2[j] = B2 + fp;
            vpm[j] = __fdividef(w, w + w2 * __expf(d));
        }
        float* p = obase + t0;
        *(v4f*)(p)          = va1;
        *(v4f*)(p + bt)     = vb1;
        *(v4f*)(p + 2 * bt) = va2;
        *(v4f*)(p + 3 * bt) = vb2;
        *(v4f*)(p + 4 * bt) = vpm;

        carry_s += total;
        carry_d += totald;
        cur = nxt;
    }
}

extern "C" void kernel_launch(void* const* d_in, const int* in_sizes, int n_in,
                              void* d_out, int out_size, void* d_ws, size_t ws_size,
                              hipStream_t stream) {
    const float* obs    = (const float*)d_in[0];
    const float* alpha1 = (const float*)d_in[1];
    const float* beta1  = (const float*)d_in[2];
    const float* alpha2 = (const float*)d_in[3];
    const float* beta2  = (const float*)d_in[4];
    const float* mixw   = (const float*)d_in[5];

    const int Bn = in_sizes[1];
    const int Tn = in_sizes[0] / Bn;
    const size_t bt = (size_t)Bn * (size_t)Tn;

    if (Tn == 8192) {
        bbm_oneshot<<<Bn, BLOCK, 0, stream>>>(obs, alpha1, beta1, alpha2, beta2,
                                              mixw, (float*)d_out, bt);
    } else {
        bbm_generic<<<Bn, GBLOCK, 0, stream>>>(obs, alpha1, beta1, alpha2, beta2,
                                               mixw, (float*)d_out, Tn, bt);
    }
}